// Round 1
// baseline (225.492 us; speedup 1.0000x reference)
//
#include <hip/hip_runtime.h>

typedef __bf16 bf16x8 __attribute__((ext_vector_type(8)));
typedef float f32x4 __attribute__((ext_vector_type(4)));

#define TWO_LOG2E 2.88539008177792681f   // 2 * log2(e): exp(2*x) = exp2(x * TWO_LOG2E)
#define LDA 72                            // padded LDS row stride (bf16 elems): 64 + 8

__device__ __forceinline__ unsigned short f2bf(float f) {
    unsigned int u = __float_as_uint(f);
    u = (u + 0x7FFFu + ((u >> 16) & 1u)) >> 16;   // RNE
    return (unsigned short)u;
}

// ---------------- kernel 1: row-normalize z=[z1;z2] -> bf16 zn[8192][256] ---------------
__global__ void normalize_kernel(const float* __restrict__ z1,
                                 const float* __restrict__ z2,
                                 unsigned short* __restrict__ zn) {
    const int wave = threadIdx.x >> 6, lane = threadIdx.x & 63;
    const int row = (blockIdx.x << 2) + wave;               // 2048 blocks * 4 rows
    const float* src = (row < 4096) ? (z1 + row * 256) : (z2 + (row - 4096) * 256);
    float4 v = ((const float4*)src)[lane];                  // 64 lanes * 4 = 256
    float ss = v.x * v.x + v.y * v.y + v.z * v.z + v.w * v.w;
#pragma unroll
    for (int m = 32; m > 0; m >>= 1) ss += __shfl_xor(ss, m, 64);
    float scale = 1.0f / fmaxf(sqrtf(ss), 1e-8f);
    uint2 w;
    w.x = (unsigned)f2bf(v.x * scale) | ((unsigned)f2bf(v.y * scale) << 16);
    w.y = (unsigned)f2bf(v.z * scale) | ((unsigned)f2bf(v.w * scale) << 16);
    *(uint2*)(zn + row * 256 + (lane << 2)) = w;
}

// ---------------- kernel 2: S[i] += sum_j exp(2 * zn_i . zn_j) over col split -----------
// grid = (64 row-blocks of 128, 8 col-splits of 1024). block = 256 (4 waves, 2x2).
__global__ void __launch_bounds__(256, 2) simexp_kernel(
    const unsigned short* __restrict__ zn,
    float* __restrict__ S)
{
    __shared__ __align__(16) unsigned short As[128 * LDA];
    __shared__ __align__(16) unsigned short Bs[128 * LDA];

    const int tid  = threadIdx.x;
    const int lane = tid & 63;
    const int wave = tid >> 6;
    const int wr = wave >> 1;          // wave row half (0/1)
    const int wc = wave & 1;           // wave col half (0/1)
    const int q   = lane >> 4;         // quad within wave
    const int n16 = lane & 15;
    const int rowBase  = blockIdx.x << 7;
    const int colSplit = blockIdx.y << 10;

    float rowsum[4][4];
#pragma unroll
    for (int i = 0; i < 4; ++i)
#pragma unroll
        for (int j = 0; j < 4; ++j) rowsum[i][j] = 0.f;

    for (int ci = 0; ci < 8; ++ci) {
        const int colBase = colSplit + (ci << 7);
        f32x4 acc[4][4];
#pragma unroll
        for (int i = 0; i < 4; ++i)
#pragma unroll
            for (int j = 0; j < 4; ++j) acc[i][j] = (f32x4){0.f, 0.f, 0.f, 0.f};

        for (int kc = 0; kc < 4; ++kc) {            // K = 256 in chunks of 64
            uint4 ta[4], tb[4];
#pragma unroll
            for (int p = 0; p < 4; ++p) {           // 1024 uint4 per tile / 256 thr
                int idx = (p << 8) + tid;
                int r = idx >> 3, c8 = idx & 7;
                ta[p] = *(const uint4*)(zn + ((rowBase + r) << 8) + (kc << 6) + (c8 << 3));
                tb[p] = *(const uint4*)(zn + ((colBase + r) << 8) + (kc << 6) + (c8 << 3));
            }
            __syncthreads();                        // protect prior reads of As/Bs
#pragma unroll
            for (int p = 0; p < 4; ++p) {
                int idx = (p << 8) + tid;
                int r = idx >> 3, c8 = idx & 7;
                *(uint4*)(As + r * LDA + (c8 << 3)) = ta[p];
                *(uint4*)(Bs + r * LDA + (c8 << 3)) = tb[p];
            }
            __syncthreads();
#pragma unroll
            for (int ks = 0; ks < 2; ++ks) {        // 2 k-steps of 32
                const int ko = (ks << 5) + (q << 3);
                bf16x8 af[4], bfr[4];
#pragma unroll
                for (int rt = 0; rt < 4; ++rt)
                    af[rt] = *(const bf16x8*)(As + ((wr << 6) + (rt << 4) + n16) * LDA + ko);
#pragma unroll
                for (int ct = 0; ct < 4; ++ct)
                    bfr[ct] = *(const bf16x8*)(Bs + ((wc << 6) + (ct << 4) + n16) * LDA + ko);
#pragma unroll
                for (int rt = 0; rt < 4; ++rt)
#pragma unroll
                    for (int ct = 0; ct < 4; ++ct)
                        acc[rt][ct] = __builtin_amdgcn_mfma_f32_16x16x32_bf16(
                            af[rt], bfr[ct], acc[rt][ct], 0, 0, 0);
            }
        }
        // epilogue: rowsum += exp(2*dot); diag/target handled in finish kernel
#pragma unroll
        for (int rt = 0; rt < 4; ++rt)
#pragma unroll
            for (int ct = 0; ct < 4; ++ct)
#pragma unroll
                for (int r = 0; r < 4; ++r)
                    rowsum[rt][r] += __builtin_amdgcn_exp2f(acc[rt][ct][r] * TWO_LOG2E);
    }

    // reduce across the 16 column-lanes (C/D layout: col = lane&15, row = q*4+reg)
#pragma unroll
    for (int rt = 0; rt < 4; ++rt)
#pragma unroll
        for (int r = 0; r < 4; ++r) {
            float s = rowsum[rt][r];
            s += __shfl_xor(s, 1, 64);
            s += __shfl_xor(s, 2, 64);
            s += __shfl_xor(s, 4, 64);
            s += __shfl_xor(s, 8, 64);
            if (n16 == 0) {
                int grow = rowBase + (wr << 6) + (rt << 4) + (q << 2) + r;
                atomicAdd(&S[grow], s);
            }
        }
}

// ---------------- kernel 3: loss = mean( log(S_i - e^{sim_ii}) - sim_{i,target} ) -------
__global__ void finish_kernel(const unsigned short* __restrict__ zn,
                              const float* __restrict__ S,
                              float* __restrict__ out)
{
    __shared__ float vals[16];
    const int tid = threadIdx.x, lane = tid & 63, wave = tid >> 6;
    const int rib = (wave << 2) + (lane >> 4);      // 0..15 rows per block
    const int row = (blockIdx.x << 4) + rib;        // 512 blocks * 16 rows
    const int tar = (row + 4096) & 8191;
    const int l16 = lane & 15;

    float drr = 0.f, drt = 0.f;
#pragma unroll
    for (int i = 0; i < 4; ++i) {
        int k = (i << 6) + (l16 << 2);
        uint2 ur = *(const uint2*)(zn + (row << 8) + k);
        uint2 ut = *(const uint2*)(zn + (tar << 8) + k);
        float a0 = __uint_as_float(ur.x << 16);
        float a1 = __uint_as_float(ur.x & 0xFFFF0000u);
        float a2 = __uint_as_float(ur.y << 16);
        float a3 = __uint_as_float(ur.y & 0xFFFF0000u);
        float b0 = __uint_as_float(ut.x << 16);
        float b1 = __uint_as_float(ut.x & 0xFFFF0000u);
        float b2 = __uint_as_float(ut.y << 16);
        float b3 = __uint_as_float(ut.y & 0xFFFF0000u);
        drr += a0 * a0 + a1 * a1 + a2 * a2 + a3 * a3;
        drt += a0 * b0 + a1 * b1 + a2 * b2 + a3 * b3;
    }
#pragma unroll
    for (int m = 1; m <= 8; m <<= 1) {
        drr += __shfl_xor(drr, m, 64);
        drt += __shfl_xor(drt, m, 64);
    }
    if (l16 == 0) {
        float Sv = S[row] - __builtin_amdgcn_exp2f(drr * TWO_LOG2E);  // remove diagonal
        vals[rib] = 0.693147180559945f * __builtin_amdgcn_logf(Sv) - 2.0f * drt;
    }
    __syncthreads();
    if (tid == 0) {
        float s = 0.f;
#pragma unroll
        for (int i = 0; i < 16; ++i) s += vals[i];
        atomicAdd(out, s * (1.0f / 8192.0f));
    }
}

extern "C" void kernel_launch(void* const* d_in, const int* in_sizes, int n_in,
                              void* d_out, int out_size, void* d_ws, size_t ws_size,
                              hipStream_t stream)
{
    const float* z1 = (const float*)d_in[0];
    const float* z2 = (const float*)d_in[1];
    unsigned short* zn = (unsigned short*)d_ws;                       // 8192*256 bf16 = 4 MB
    float* S = (float*)((char*)d_ws + 8192 * 256 * sizeof(unsigned short)); // 32 KB
    float* out = (float*)d_out;

    hipMemsetAsync(S, 0, 8192 * sizeof(float), stream);
    hipMemsetAsync(out, 0, sizeof(float), stream);

    normalize_kernel<<<2048, 256, 0, stream>>>(z1, z2, zn);
    dim3 grid(64, 8);
    simexp_kernel<<<grid, 256, 0, stream>>>(zn, S);
    finish_kernel<<<512, 256, 0, stream>>>(zn, S, out);
}

// Round 2
// 125.984 us; speedup vs baseline: 1.7898x; 1.7898x over previous
//
#include <hip/hip_runtime.h>

typedef __bf16 bf16x8 __attribute__((ext_vector_type(8)));
typedef float f32x4 __attribute__((ext_vector_type(4)));

#define TWO_LOG2E 2.88539008177792681f   // 2 * log2(e): exp(2*x) = exp2(x * TWO_LOG2E)

#define GLOADLDS16(g, l) __builtin_amdgcn_global_load_lds(                     \
    (const __attribute__((address_space(1))) void*)(g),                        \
    (__attribute__((address_space(3))) void*)(l), 16, 0, 0)

__device__ __forceinline__ unsigned short f2bf(float f) {
    unsigned int u = __float_as_uint(f);
    u = (u + 0x7FFFu + ((u >> 16) & 1u)) >> 16;   // RNE
    return (unsigned short)u;
}

// ---------------- kernel 1: row-normalize z=[z1;z2] -> bf16 zn[8192][256] ---------------
__global__ void normalize_kernel(const float* __restrict__ z1,
                                 const float* __restrict__ z2,
                                 unsigned short* __restrict__ zn) {
    const int wave = threadIdx.x >> 6, lane = threadIdx.x & 63;
    const int row = (blockIdx.x << 2) + wave;               // 2048 blocks * 4 rows
    const float* src = (row < 4096) ? (z1 + row * 256) : (z2 + (row - 4096) * 256);
    float4 v = ((const float4*)src)[lane];                  // 64 lanes * 4 = 256
    float ss = v.x * v.x + v.y * v.y + v.z * v.z + v.w * v.w;
#pragma unroll
    for (int m = 32; m > 0; m >>= 1) ss += __shfl_xor(ss, m, 64);
    float scale = 1.0f / fmaxf(sqrtf(ss), 1e-8f);
    uint2 w;
    w.x = (unsigned)f2bf(v.x * scale) | ((unsigned)f2bf(v.y * scale) << 16);
    w.y = (unsigned)f2bf(v.z * scale) | ((unsigned)f2bf(v.w * scale) << 16);
    *(uint2*)(zn + row * 256 + (lane << 2)) = w;
}

// ---------------- kernel 2: triangular tile (bi<=bj): S[i] += sum_j exp(2 zn_i.zn_j) ----
// One 128x128 tile per block. Off-diagonal tiles also add their transposed
// contribution via column sums (sim is symmetric). 2080 blocks, 256 threads.
// LDS: unpadded 128x64 bf16 tiles, XOR-swizzled in 16B units via the global
// source address (global_load_lds forces dest = base + lane*16).
__global__ void __launch_bounds__(256) simexp_kernel(
    const unsigned short* __restrict__ zn,
    float* __restrict__ S)
{
    __shared__ __align__(16) unsigned short As[128 * 64];
    __shared__ __align__(16) unsigned short Bs[128 * 64];

    const int tid  = threadIdx.x;
    const int lane = tid & 63;
    const int wave = tid >> 6;
    const int wr = wave >> 1;          // wave row half (0/1)
    const int wc = wave & 1;           // wave col half (0/1)
    const int q   = lane >> 4;         // quad within wave
    const int n16 = lane & 15;

    // triangular decode: blockIdx.x -> (bi, bj), bi <= bj, 64 row-tiles
    int t = blockIdx.x, bi = 0;
    while (t >= 64 - bi) { t -= 64 - bi; ++bi; }
    const int bj = bi + t;
    const int rowBase = bi << 7;
    const int colBase = bj << 7;

    // staging lane mapping
    const int lrow = lane >> 3;                 // 0..7 row within 8-row segment
    const int k8s  = (lane & 7) ^ lrow;         // swizzled source 16B chunk

    f32x4 acc[4][4];
#pragma unroll
    for (int i = 0; i < 4; ++i)
#pragma unroll
        for (int j = 0; j < 4; ++j) acc[i][j] = (f32x4){0.f, 0.f, 0.f, 0.f};

    for (int kc = 0; kc < 4; ++kc) {            // K = 256 in chunks of 64
        __syncthreads();                        // prior ds_reads done before overwrite
#pragma unroll
        for (int p = 0; p < 4; ++p) {
            const int seg = (wave << 2) + p;    // 0..15, 1KB segment of the tile
            const int r = (seg << 3) + lrow;    // row 0..127
            const unsigned short* ga = zn + ((rowBase + r) << 8) + (kc << 6) + (k8s << 3);
            const unsigned short* gb = zn + ((colBase + r) << 8) + (kc << 6) + (k8s << 3);
            GLOADLDS16(ga, As + (seg << 9) + (lane << 3));
            GLOADLDS16(gb, Bs + (seg << 9) + (lane << 3));
        }
        __syncthreads();                        // staging complete (vmcnt drained)
#pragma unroll
        for (int ks = 0; ks < 2; ++ks) {        // 2 k-steps of 32
            bf16x8 af[4], bfr[4];
#pragma unroll
            for (int rt = 0; rt < 4; ++rt) {
                const int ar = (wr << 6) + (rt << 4) + n16;
                const int kk = ((ks << 2) + q) ^ (n16 & 7);
                af[rt] = *(const bf16x8*)(As + (ar << 6) + (kk << 3));
            }
#pragma unroll
            for (int ct = 0; ct < 4; ++ct) {
                const int br = (wc << 6) + (ct << 4) + n16;
                const int kk = ((ks << 2) + q) ^ (n16 & 7);
                bfr[ct] = *(const bf16x8*)(Bs + (br << 6) + (kk << 3));
            }
#pragma unroll
            for (int rt = 0; rt < 4; ++rt)
#pragma unroll
                for (int ct = 0; ct < 4; ++ct)
                    acc[rt][ct] = __builtin_amdgcn_mfma_f32_16x16x32_bf16(
                        af[rt], bfr[ct], acc[rt][ct], 0, 0, 0);
        }
    }

    // epilogue: e = exp(2*dot); row sums always, col sums for off-diag tiles
    float rs[4][4];                              // per (rt, r)
    float cs[4];                                 // per ct
#pragma unroll
    for (int i = 0; i < 4; ++i) {
        cs[i] = 0.f;
#pragma unroll
        for (int j = 0; j < 4; ++j) rs[i][j] = 0.f;
    }
#pragma unroll
    for (int rt = 0; rt < 4; ++rt)
#pragma unroll
        for (int ct = 0; ct < 4; ++ct)
#pragma unroll
            for (int r = 0; r < 4; ++r) {
                float e = __builtin_amdgcn_exp2f(acc[rt][ct][r] * TWO_LOG2E);
                rs[rt][r] += e;
                cs[ct] += e;
            }

    // row sums: reduce across 16 col-lanes (C/D layout: col=lane&15, row=q*4+r)
#pragma unroll
    for (int rt = 0; rt < 4; ++rt)
#pragma unroll
        for (int r = 0; r < 4; ++r) {
            float s = rs[rt][r];
            s += __shfl_xor(s, 1, 64);
            s += __shfl_xor(s, 2, 64);
            s += __shfl_xor(s, 4, 64);
            s += __shfl_xor(s, 8, 64);
            if (n16 == 0) {
                int grow = rowBase + (wr << 6) + (rt << 4) + (q << 2) + r;
                atomicAdd(&S[grow], s);
            }
        }
    // col sums: reduce across the 4 quads (rows) -> lanes q==0 hold col n16
    if (bi != bj) {
#pragma unroll
        for (int ct = 0; ct < 4; ++ct) {
            float s = cs[ct];
            s += __shfl_xor(s, 16, 64);
            s += __shfl_xor(s, 32, 64);
            if (q == 0) {
                int gcol = colBase + (wc << 6) + (ct << 4) + n16;
                atomicAdd(&S[gcol], s);
            }
        }
    }
}

// ---------------- kernel 3: loss = mean( log(S_i - e^{sim_ii}) - sim_{i,target} ) -------
__global__ void finish_kernel(const unsigned short* __restrict__ zn,
                              const float* __restrict__ S,
                              float* __restrict__ out)
{
    __shared__ float vals[16];
    const int tid = threadIdx.x, lane = tid & 63, wave = tid >> 6;
    const int rib = (wave << 2) + (lane >> 4);      // 0..15 rows per block
    const int row = (blockIdx.x << 4) + rib;        // 512 blocks * 16 rows
    const int tar = (row + 4096) & 8191;
    const int l16 = lane & 15;

    float drr = 0.f, drt = 0.f;
#pragma unroll
    for (int i = 0; i < 4; ++i) {
        int k = (i << 6) + (l16 << 2);
        uint2 ur = *(const uint2*)(zn + (row << 8) + k);
        uint2 ut = *(const uint2*)(zn + (tar << 8) + k);
        float a0 = __uint_as_float(ur.x << 16);
        float a1 = __uint_as_float(ur.x & 0xFFFF0000u);
        float a2 = __uint_as_float(ur.y << 16);
        float a3 = __uint_as_float(ur.y & 0xFFFF0000u);
        float b0 = __uint_as_float(ut.x << 16);
        float b1 = __uint_as_float(ut.x & 0xFFFF0000u);
        float b2 = __uint_as_float(ut.y << 16);
        float b3 = __uint_as_float(ut.y & 0xFFFF0000u);
        drr += a0 * a0 + a1 * a1 + a2 * a2 + a3 * a3;
        drt += a0 * b0 + a1 * b1 + a2 * b2 + a3 * b3;
    }
#pragma unroll
    for (int m = 1; m <= 8; m <<= 1) {
        drr += __shfl_xor(drr, m, 64);
        drt += __shfl_xor(drt, m, 64);
    }
    if (l16 == 0) {
        float Sv = S[row] - __builtin_amdgcn_exp2f(drr * TWO_LOG2E);  // remove diagonal
        vals[rib] = 0.693147180559945f * __builtin_amdgcn_logf(Sv) - 2.0f * drt;
    }
    __syncthreads();
    if (tid == 0) {
        float s = 0.f;
#pragma unroll
        for (int i = 0; i < 16; ++i) s += vals[i];
        atomicAdd(out, s * (1.0f / 8192.0f));
    }
}

extern "C" void kernel_launch(void* const* d_in, const int* in_sizes, int n_in,
                              void* d_out, int out_size, void* d_ws, size_t ws_size,
                              hipStream_t stream)
{
    const float* z1 = (const float*)d_in[0];
    const float* z2 = (const float*)d_in[1];
    unsigned short* zn = (unsigned short*)d_ws;                       // 8192*256 bf16 = 4 MB
    float* S = (float*)((char*)d_ws + 8192 * 256 * sizeof(unsigned short)); // 32 KB
    float* out = (float*)d_out;

    hipMemsetAsync(S, 0, 8192 * sizeof(float), stream);
    hipMemsetAsync(out, 0, sizeof(float), stream);

    normalize_kernel<<<2048, 256, 0, stream>>>(z1, z2, zn);
    simexp_kernel<<<2080, 256, 0, stream>>>(zn, S);
    finish_kernel<<<512, 256, 0, stream>>>(zn, S, out);
}